// Round 1
// baseline (11568.832 us; speedup 1.0000x reference)
//
#include <hip/hip_runtime.h>

// LSTM T=512 B=64 IN=512 H=512 L=2, fp32 in/out.
// Strategy: one kernel launch per pipelined timestep (513 launches); kernel
// boundaries give the device-wide sync the recurrence needs. Each launch runs
// unit0 = layer0 @ t (blocks 0..31) and unit1 = layer1 @ t-1 (blocks 32..63).
// Per unit: ifgo = [inp | h_prev](64x1024) @ Wcat^T(2048x1024) + bh, via
// bf16 16x16x32 MFMA, fp32 state math. Weights/x converted to bf16 in ws.

typedef unsigned short u16;
typedef unsigned int u32;
typedef __attribute__((ext_vector_type(8))) short bf16x8;
typedef __attribute__((ext_vector_type(4))) float floatx4;

#define T_ 512
#define B_ 64
#define H_ 512

__device__ __forceinline__ u16 f2bf(float f) {
  u32 u = __float_as_uint(f);
  u32 r = (u + 0x7fffu + ((u >> 16) & 1u)) >> 16;  // RNE
  return (u16)r;
}

__device__ __forceinline__ float sigm(float x) { return 1.f / (1.f + __expf(-x)); }

__device__ __forceinline__ float tanh_(float x) {
  float ax = fabsf(x);
  float e = __expf(-2.f * ax);          // <= 1, no overflow
  float t = (1.f - e) / (1.f + e);
  return copysignf(t, x);
}

// Wcat[l][row 0..2047][k 0..1023] bf16, row-major: k<512 from Wx, k>=512 from Wh.
__global__ void conv_w_kernel(const float* __restrict__ Wx, const float* __restrict__ Wh,
                              u16* __restrict__ Wcat) {
  int i = blockIdx.x * 256 + threadIdx.x;  // 1,048,576 threads, 4 elems each
  int base = i * 4;
  int k = base & 1023;
  int row = base >> 10;  // l*2048 + j
  const float* src = (k < 512) ? (Wx + row * 512 + k) : (Wh + row * 512 + (k - 512));
  float4 v = *(const float4*)src;
  uint2 p;
  p.x = (u32)f2bf(v.x) | ((u32)f2bf(v.y) << 16);
  p.y = (u32)f2bf(v.z) | ((u32)f2bf(v.w) << 16);
  *(uint2*)(Wcat + base) = p;
}

__global__ void conv_x_kernel(const float4* __restrict__ x, u16* __restrict__ xb) {
  int i = blockIdx.x * 256 + threadIdx.x;  // 4,194,304 threads, 4 elems each
  float4 v = x[i];
  uint2 p;
  p.x = (u32)f2bf(v.x) | ((u32)f2bf(v.y) << 16);
  p.y = (u32)f2bf(v.z) | ((u32)f2bf(v.w) << 16);
  *(uint2*)(xb + i * 4) = p;
}

// Grid 64 x 256. blockIdx>>5 = unit (layer), blockIdx&31 = 16-col slice of H.
// Wave w handles gate w: 64 rows x 16 cols, K-loop over 1024 (skip h half at time 0).
__global__ __launch_bounds__(256) void lstm_step(
    const u16* __restrict__ Wcat,   // [2][2048][1024] bf16
    const float* __restrict__ bh,   // [2][2048]
    const u16* __restrict__ xb,     // [512][64][512] bf16
    u16* __restrict__ h0b,          // [2][64][512] bf16 ping-pong
    u16* __restrict__ h1b,          // [2][64][512]
    float* __restrict__ c0,         // [64][512]
    float* __restrict__ c1,
    float* __restrict__ out,        // d_out: out[512][64][512] ++ h[2][64][512] ++ c[2][64][512]
    int t) {
  const int unit = blockIdx.x >> 5;
  const int blk = blockIdx.x & 31;
  if (unit == 0 && t >= T_) return;   // t in [0,512]; unit0 active t<=511
  if (unit == 1 && t < 1) return;     // unit1 handles time t-1
  const int time = (unit == 0) ? t : t - 1;
  const int l = unit;

  const u16* inp;    // [64][512] bf16: x_t (l0) or h0_t (l1)
  const u16* hprev;  // [64][512] bf16: h_{time-1} of this layer (valid if time>0)
  u16* hout;
  float* cbuf;
  if (unit == 0) {
    inp = xb + (size_t)time * (B_ * H_);
    hprev = h0b + ((time + 1) & 1) * (B_ * H_);
    hout = h0b + (time & 1) * (B_ * H_);
    cbuf = c0;
  } else {
    inp = h0b + (time & 1) * (B_ * H_);          // h0 at same time, written by prev kernel
    hprev = h1b + ((time + 1) & 1) * (B_ * H_);
    hout = h1b + (time & 1) * (B_ * H_);
    cbuf = c1;
  }
  const bool has_h = (time > 0);

  const int wave = threadIdx.x >> 6;  // gate: 0=i 1=f 2=g 3=o
  const int lane = threadIdx.x & 63;
  const int nl = lane & 15;
  const int quad = lane >> 4;

  // B operand: W row = l*2048 + gate*512 + blk*16 + nl; lane reads k = quad*8 + j
  const u16* wrow = Wcat + ((size_t)l * 2048 + wave * 512 + blk * 16 + nl) * 1024 + quad * 8;

  floatx4 acc[4] = {floatx4{0.f, 0.f, 0.f, 0.f}, floatx4{0.f, 0.f, 0.f, 0.f},
                    floatx4{0.f, 0.f, 0.f, 0.f}, floatx4{0.f, 0.f, 0.f, 0.f}};

  // ---- first K half: inp (always) ----
  {
    const u16* abase = inp + quad * 8;
#pragma unroll 4
    for (int kk = 0; kk < 512; kk += 32) {
      bf16x8 bfrag = *(const bf16x8*)(wrow + kk);
#pragma unroll
      for (int r = 0; r < 4; ++r) {
        bf16x8 afrag = *(const bf16x8*)(abase + (r * 16 + nl) * H_ + kk);
        acc[r] = __builtin_amdgcn_mfma_f32_16x16x32_bf16(afrag, bfrag, acc[r], 0, 0, 0);
      }
    }
  }
  // ---- second K half: h_prev (skip at time 0) ----
  if (has_h) {
    const u16* abase = hprev + quad * 8;
#pragma unroll 4
    for (int kk = 0; kk < 512; kk += 32) {
      bf16x8 bfrag = *(const bf16x8*)(wrow + 512 + kk);
#pragma unroll
      for (int r = 0; r < 4; ++r) {
        bf16x8 afrag = *(const bf16x8*)(abase + (r * 16 + nl) * H_ + kk);
        acc[r] = __builtin_amdgcn_mfma_f32_16x16x32_bf16(afrag, bfrag, acc[r], 0, 0, 0);
      }
    }
  }

  // ---- combine gates via LDS ----
  // C/D layout (verified m89): col = lane&15, row(in 16-tile) = quad*4 + i.
  float bias = bh[l * 2048 + wave * 512 + blk * 16 + nl];
  __shared__ float lds[4][64][17];  // +1 pad vs 16 to spread banks
#pragma unroll
  for (int r = 0; r < 4; ++r)
#pragma unroll
    for (int i = 0; i < 4; ++i)
      lds[wave][r * 16 + quad * 4 + i][nl] = acc[r][i] + bias;
  __syncthreads();

  const size_t out_h_base = (size_t)T_ * B_ * H_;
  const size_t out_c_base = out_h_base + (size_t)2 * B_ * H_;
#pragma unroll
  for (int rr = 0; rr < 4; ++rr) {
    int row = rr * 16 + (threadIdx.x >> 4);  // 0..63 (batch)
    int col = threadIdx.x & 15;              // 0..15 within slice
    float pi = lds[0][row][col];
    float pf = lds[1][row][col];
    float pg = lds[2][row][col];
    float po = lds[3][row][col];
    int hcol = blk * 16 + col;
    size_t sidx = (size_t)row * H_ + hcol;
    float cprev = has_h ? cbuf[sidx] : 0.f;
    float ig = sigm(pi);
    float fg = sigm(pf);
    float gg = tanh_(pg);
    float og = sigm(po);
    float cn = fg * cprev + ig * gg;
    float hn = og * tanh_(cn);
    cbuf[sidx] = cn;
    hout[sidx] = f2bf(hn);
    if (unit == 1) out[(size_t)time * (B_ * H_) + sidx] = hn;  // out = layer-1 h
    if (time == T_ - 1) {
      out[out_h_base + (size_t)l * (B_ * H_) + sidx] = hn;
      out[out_c_base + (size_t)l * (B_ * H_) + sidx] = cn;
    }
  }
}

extern "C" void kernel_launch(void* const* d_in, const int* in_sizes, int n_in,
                              void* d_out, int out_size, void* d_ws, size_t ws_size,
                              hipStream_t stream) {
  const float* x = (const float*)d_in[0];
  const float* Wx = (const float*)d_in[1];
  const float* Wh = (const float*)d_in[2];
  const float* bh = (const float*)d_in[3];
  float* out = (float*)d_out;
  char* ws = (char*)d_ws;

  // ws layout (bytes):
  u16* Wcat = (u16*)ws;                            // 2*2048*1024*2 = 8,388,608
  u16* xb = (u16*)(ws + 8388608);                  // 512*64*512*2 = 33,554,432
  u16* h0b = (u16*)(ws + 8388608 + 33554432);      // 2*64*512*2   = 131,072
  u16* h1b = (u16*)(ws + 8388608 + 33554432 + 131072);
  float* c0 = (float*)(ws + 8388608 + 33554432 + 2 * 131072);   // 131,072
  float* c1 = (float*)(ws + 8388608 + 33554432 + 3 * 131072);
  // total ~42.2 MB

  conv_w_kernel<<<4096, 256, 0, stream>>>(Wx, Wh, Wcat);
  conv_x_kernel<<<16384, 256, 0, stream>>>((const float4*)x, xb);

  for (int t = 0; t <= T_; ++t) {
    lstm_step<<<64, 256, 0, stream>>>(Wcat, bh, xb, h0b, h1b, c0, c1, out, t);
  }
}